// Round 12
// baseline (260.931 us; speedup 1.0000x reference)
//
#include <hip/hip_runtime.h>

#define NPTS 20000
#define EPSF 1e-5f

typedef _Float16 half8 __attribute__((ext_vector_type(8)));
typedef float floatx4 __attribute__((ext_vector_type(4)));

// ---------------------------------------------------------------------------
// B-fragment: frag[j] = W[32ks+8g+j][16nt+c15], from swizzled fp16 weights:
//   [k][d] -> d*64 + (((k>>3)^(d&7))<<3) + (k&7)
// ---------------------------------------------------------------------------
__device__ __forceinline__ half8 ldWt(const _Float16* __restrict__ w,
                                      int c15, int g, int nt, int ks) {
  int c = nt * 16 + c15;
  int kg = ks * 4 + g;
  return *(const half8*)(w + c * 64 + ((kg ^ (c & 7)) << 3));
}

// B-fragment directly from fp32 row-major W (one-shot use, L2-hot)
__device__ __forceinline__ half8 ldWtF32(const float* __restrict__ W,
                                         int c15, int g, int nt, int ks) {
  int c = nt * 16 + c15;
  half8 r;
#pragma unroll
  for (int j = 0; j < 8; ++j) r[j] = (_Float16)W[(ks * 32 + g * 8 + j) * 64 + c];
  return r;
}

// Per-wave transpose buffer T: 64 cols x 32 rows fp32, XOR-swizzled chunks:
// [col][row] -> col*32 + (((row>>2)^(col&7))<<2) + (row&3)
__device__ __forceinline__ void stC(float* __restrict__ Tw, int c15, int g,
                                    int mt, int nt, floatx4 v) {
  int col = nt * 16 + c15;
  int chunk = mt * 4 + g;
  *(floatx4*)(Tw + col * 32 + ((chunk ^ (col & 7)) << 2)) = v;
}

__device__ __forceinline__ floatx4 ldCread(const float* __restrict__ Tw,
                                           int c15, int g, int mt, int nt) {
  int col = nt * 16 + c15;
  int chunk = mt * 4 + g;
  return *(const floatx4*)(Tw + col * 32 + ((chunk ^ (col & 7)) << 2));
}

// A-fragment from T: frag[j] = X[16mt+c15][32ks+8g+j] (fp32 -> fp16)
__device__ __forceinline__ half8 ldA(const float* __restrict__ Tw,
                                     int c15, int g, int mt, int ks) {
  int m = mt * 16 + c15;
  half8 r;
#pragma unroll
  for (int j = 0; j < 8; ++j) {
    int c = ks * 32 + g * 8 + j;                // c&7 == j
    r[j] = (_Float16)Tw[c * 32 + (((m >> 2) ^ j) << 2) + (m & 3)];
  }
  return r;
}

__device__ __forceinline__ void ldAfrags(const float* __restrict__ Tw,
                                         int c15, int g, half8 a[2][2]) {
#pragma unroll
  for (int mt = 0; mt < 2; ++mt)
#pragma unroll
    for (int ks = 0; ks < 2; ++ks) a[mt][ks] = ldA(Tw, c15, g, mt, ks);
}

__device__ __forceinline__ void domm(const _Float16* __restrict__ w,
                                     const half8 a[2][2], int c15, int g,
                                     floatx4 acc[2][4]) {
#pragma unroll
  for (int ks = 0; ks < 2; ++ks)
#pragma unroll
    for (int nt = 0; nt < 4; ++nt) {
      half8 b = ldWt(w, c15, g, nt, ks);
#pragma unroll
      for (int mt = 0; mt < 2; ++mt)
        acc[mt][nt] = __builtin_amdgcn_mfma_f32_16x16x32_f16(a[mt][ks], b, acc[mt][nt], 0, 0, 0);
    }
}

// single-mt (16-row) variant for gconv
__device__ __forceinline__ void domm1(const _Float16* __restrict__ w,
                                      const half8 a[2], int c15, int g,
                                      floatx4 acc[4]) {
#pragma unroll
  for (int ks = 0; ks < 2; ++ks)
#pragma unroll
    for (int nt = 0; nt < 4; ++nt) {
      half8 b = ldWt(w, c15, g, nt, ks);
      acc[nt] = __builtin_amdgcn_mfma_f32_16x16x32_f16(a[ks], b, acc[nt], 0, 0, 0);
    }
}

// ---------------------------------------------------------------------------
// Fused weight-prep (blocks 0..6) + Q precompute (blocks 7..163).
// prep order: Wl2, Wv, Wk, Ww1, Ww2, Wsg[0:64], Wf
// ---------------------------------------------------------------------------
__global__ __launch_bounds__(256) void prep_q_kernel(
    const float* __restrict__ Wl2, const float* __restrict__ Wv,
    const float* __restrict__ Wk, const float* __restrict__ Ww1,
    const float* __restrict__ Ww2, const float* __restrict__ Wsg,
    const float* __restrict__ Wf, const float* __restrict__ Wq,
    const float* __restrict__ feats, const float* __restrict__ bq,
    _Float16* __restrict__ wtg, _Float16* __restrict__ Qh)
{
  if (blockIdx.x < 7) {
    const float* srcs[7] = {Wl2, Wv, Wk, Ww1, Ww2, Wsg, Wf};
    const float* src = srcs[blockIdx.x];
    _Float16* dst = wtg + blockIdx.x * 4096;
    int t = threadIdx.x;
#pragma unroll
    for (int i = 0; i < 16; ++i) {
      int lin = i * 256 + t;            // = k*64 + d
      int k = lin >> 6, d = lin & 63;
      dst[d * 64 + (((k >> 3) ^ (d & 7)) << 3) + (k & 7)] = (_Float16)src[lin];
    }
    return;
  }
  // ---- Q = relu(feats @ Wq + bq), 32 points/wave ----
  const int wv = threadIdx.x >> 6, lane = threadIdx.x & 63;
  const int c15 = lane & 15, g = lane >> 4;
  const int n0 = ((blockIdx.x - 7) * 4 + wv) * 32;

  half8 a[2][2];
#pragma unroll
  for (int mt = 0; mt < 2; ++mt) {
    int r = n0 + mt * 16 + c15;
    if (r > NPTS - 1) r = NPTS - 1;
#pragma unroll
    for (int ks = 0; ks < 2; ++ks) {
      const float* p = feats + (size_t)r * 64 + ks * 32 + g * 8;
      float4 u0 = *(const float4*)p, u1 = *(const float4*)(p + 4);
      a[mt][ks][0] = (_Float16)u0.x; a[mt][ks][1] = (_Float16)u0.y;
      a[mt][ks][2] = (_Float16)u0.z; a[mt][ks][3] = (_Float16)u0.w;
      a[mt][ks][4] = (_Float16)u1.x; a[mt][ks][5] = (_Float16)u1.y;
      a[mt][ks][6] = (_Float16)u1.z; a[mt][ks][7] = (_Float16)u1.w;
    }
  }
  floatx4 acc[2][4] = {};
#pragma unroll
  for (int ks = 0; ks < 2; ++ks)
#pragma unroll
    for (int nt = 0; nt < 4; ++nt) {
      half8 b = ldWtF32(Wq, c15, g, nt, ks);
#pragma unroll
      for (int mt = 0; mt < 2; ++mt)
        acc[mt][nt] = __builtin_amdgcn_mfma_f32_16x16x32_f16(a[mt][ks], b, acc[mt][nt], 0, 0, 0);
    }
#pragma unroll
  for (int nt = 0; nt < 4; ++nt) {
    float bqv = bq[nt * 16 + c15];
#pragma unroll
    for (int mt = 0; mt < 2; ++mt)
#pragma unroll
      for (int r = 0; r < 4; ++r) {
        int n = n0 + mt * 16 + g * 4 + r;
        if (n < NPTS)
          Qh[(size_t)n * 64 + nt * 16 + c15] = (_Float16)fmaxf(acc[mt][nt][r] + bqv, 0.f);
      }
  }
}

// ---------------------------------------------------------------------------
// Kernel A: fused per-point attention; one wave per point, MFMA matmuls.
// R12 probe: (256,5) — occupancy is register-capped at 4 waves/SIMD with
// (256,4); LDS allows 5 blocks/CU. Trading possible modest spill for +25%
// latency hiding. R4 evidence: hidden spill costs ~3.5 µs; occupancy loss
// (R5) cost ~8 µs. If this regresses, R11's (256,4) is the final state.
// ---------------------------------------------------------------------------
__global__ __launch_bounds__(256, 5) void attn_kernel(
    const float* __restrict__ coords, const float* __restrict__ feats,
    const float* __restrict__ bk, const float* __restrict__ bv,
    const float* __restrict__ Wl1, const float* __restrict__ bl1,
    const float* __restrict__ bl2, const float* __restrict__ bw1,
    const float* __restrict__ bw2, const float* __restrict__ g_att,
    const float* __restrict__ b_att, const int* __restrict__ knn,
    const _Float16* __restrict__ wtg, const _Float16* __restrict__ Qh,
    _Float16* __restrict__ h_out)
{
  __shared__ float Tsh[4][2048];
  const int wv = threadIdx.x >> 6, lane = threadIdx.x & 63;
  const int c15 = lane & 15, g = lane >> 4;
  const int n = blockIdx.x * 4 + wv;
  float* Tw = Tsh[wv];
  const int* row = knn + (size_t)n * 33;

  const _Float16* wt_l2 = wtg;
  const _Float16* wt_v  = wtg + 4096;
  const _Float16* wt_k  = wtg + 8192;
  const _Float16* wt_w1 = wtg + 12288;
  const _Float16* wt_w2 = wtg + 16384;

  // ---- h1 = relu(diff @ Wl1 + bl1), built directly in A-layout ----
  half8 aH[2][2];
  {
    float cnx = coords[(size_t)n * 3], cny = coords[(size_t)n * 3 + 1],
          cnz = coords[(size_t)n * 3 + 2];
#pragma unroll
    for (int ks = 0; ks < 2; ++ks) {
      int c0 = ks * 32 + g * 8;
      float4 wx0 = *(const float4*)(Wl1 + c0),       wx1 = *(const float4*)(Wl1 + c0 + 4);
      float4 wy0 = *(const float4*)(Wl1 + 64 + c0),  wy1 = *(const float4*)(Wl1 + 64 + c0 + 4);
      float4 wz0 = *(const float4*)(Wl1 + 128 + c0), wz1 = *(const float4*)(Wl1 + 128 + c0 + 4);
      float4 bb0 = *(const float4*)(bl1 + c0),       bb1 = *(const float4*)(bl1 + c0 + 4);
      float wx[8] = {wx0.x,wx0.y,wx0.z,wx0.w,wx1.x,wx1.y,wx1.z,wx1.w};
      float wy[8] = {wy0.x,wy0.y,wy0.z,wy0.w,wy1.x,wy1.y,wy1.z,wy1.w};
      float wz[8] = {wz0.x,wz0.y,wz0.z,wz0.w,wz1.x,wz1.y,wz1.z,wz1.w};
      float bb[8] = {bb0.x,bb0.y,bb0.z,bb0.w,bb1.x,bb1.y,bb1.z,bb1.w};
#pragma unroll
      for (int mt = 0; mt < 2; ++mt) {
        int id = row[mt * 16 + c15];
        float dx = coords[(size_t)id * 3] - cnx;
        float dy = coords[(size_t)id * 3 + 1] - cny;
        float dz = coords[(size_t)id * 3 + 2] - cnz;
#pragma unroll
        for (int j = 0; j < 8; ++j)
          aH[mt][ks][j] = (_Float16)fmaxf(dx * wx[j] + dy * wy[j] + dz * wz[j] + bb[j], 0.f);
      }
    }
  }

  // ---- fc = h1 @ Wl2 + bl2 -> straight to T (accs die here) ----
  {
    floatx4 fcacc[2][4] = {};
    domm(wt_l2, aH, c15, g, fcacc);
#pragma unroll
    for (int nt = 0; nt < 4; ++nt) {
      float b = bl2[nt * 16 + c15];
#pragma unroll
      for (int mt = 0; mt < 2; ++mt) stC(Tw, c15, g, mt, nt, fcacc[mt][nt] + b);
    }
  }
  __builtin_amdgcn_wave_barrier();

  // ---- aP = fp16(fc + feats[idx]) built directly in A-layout ----
  half8 aP[2][2];
#pragma unroll
  for (int mt = 0; mt < 2; ++mt) {
    int m = mt * 16 + c15;
    int rn = row[m];
#pragma unroll
    for (int ks = 0; ks < 2; ++ks) {
      const float* fp = feats + (size_t)rn * 64 + ks * 32 + g * 8;
      float4 u0 = *(const float4*)fp, u1 = *(const float4*)(fp + 4);
      float fv[8] = {u0.x,u0.y,u0.z,u0.w,u1.x,u1.y,u1.z,u1.w};
#pragma unroll
      for (int j = 0; j < 8; ++j) {
        int c = ks * 32 + g * 8 + j;              // c&7 == j
        float fcv = Tw[c * 32 + (((m >> 2) ^ j) << 2) + (m & 3)];
        aP[mt][ks][j] = (_Float16)(fcv + fv[j]);
      }
    }
  }
  __builtin_amdgcn_wave_barrier();

  // ---- KR = pe @ Wk ; rel = (relu(KR+bk) - Q) * fc, in place over fc ----
  {
    floatx4 KR[2][4] = {};
    domm(wt_k, aP, c15, g, KR);
    __builtin_amdgcn_wave_barrier();
#pragma unroll
    for (int nt = 0; nt < 4; ++nt) {
      float bkv = bk[nt * 16 + c15];
      float q4 = (float)Qh[(size_t)n * 64 + nt * 16 + c15];
#pragma unroll
      for (int mt = 0; mt < 2; ++mt) {
        floatx4 fcq = ldCread(Tw, c15, g, mt, nt);
        floatx4 v;
#pragma unroll
        for (int r = 0; r < 4; ++r)
          v[r] = (fmaxf(KR[mt][nt][r] + bkv, 0.f) - q4) * fcq[r];
        stC(Tw, c15, g, mt, nt, v);
      }
    }
  }
  __builtin_amdgcn_wave_barrier();
  half8 aR[2][2];
  ldAfrags(Tw, c15, g, aR);

  // ---- w1 = relu(rel @ Ww1 + bw1) -> T ----
  {
    floatx4 W1[2][4] = {};
    domm(wt_w1, aR, c15, g, W1);
    __builtin_amdgcn_wave_barrier();
#pragma unroll
    for (int nt = 0; nt < 4; ++nt) {
      float b = bw1[nt * 16 + c15];
#pragma unroll
      for (int mt = 0; mt < 2; ++mt) {
        floatx4 v;
#pragma unroll
        for (int r = 0; r < 4; ++r) v[r] = fmaxf(W1[mt][nt][r] + b, 0.f);
        stC(Tw, c15, g, mt, nt, v);
      }
    }
  }
  __builtin_amdgcn_wave_barrier();
  half8 aW[2][2];
  ldAfrags(Tw, c15, g, aW);

  // ---- w = w1 @ Ww2 + bw2 -> T ----
  {
    floatx4 WW[2][4] = {};
    domm(wt_w2, aW, c15, g, WW);
    __builtin_amdgcn_wave_barrier();
#pragma unroll
    for (int nt = 0; nt < 4; ++nt) {
      float b = bw2[nt * 16 + c15];
#pragma unroll
      for (int mt = 0; mt < 2; ++mt) stC(Tw, c15, g, mt, nt, WW[mt][nt] + b);
    }
  }
  __builtin_amdgcn_wave_barrier();

  // ---- sparsemax: lane d = lane sorts column d (from T) ----
  float tau;
  {
    float a[32];
#pragma unroll
    for (int i = 0; i < 8; ++i) {
      floatx4 ch = *(const floatx4*)(Tw + lane * 32 + ((i ^ (lane & 7)) << 2));
#pragma unroll
      for (int r = 0; r < 4; ++r) a[i * 4 + r] = ch[r];
    }
#pragma unroll
    for (int size = 2; size <= 32; size <<= 1) {
#pragma unroll
      for (int stride = size >> 1; stride > 0; stride >>= 1) {
#pragma unroll
        for (int i = 0; i < 32; ++i) {
          int j = i ^ stride;
          if (j > i) {
            float x = a[i], y = a[j];
            float lo = fminf(x, y), hi = fmaxf(x, y);
            bool up = ((i & size) == 0);
            a[i] = up ? hi : lo;
            a[j] = up ? lo : hi;
          }
        }
      }
    }
    float csum = 0.f, csel = 0.f;
    int ksup = 1;
#pragma unroll
    for (int i = 0; i < 32; ++i) {
      csum += a[i];
      if (1.0f + (float)(i + 1) * a[i] > csum) { ksup = i + 1; csel = csum; }
    }
    tau = (csel - 1.0f) / (float)ksup;
  }

  // ---- V = pe @ Wv + bv (aP still live; sort regs dead) ----
  floatx4 V[2][4] = {};
  domm(wt_v, aP, c15, g, V);
#pragma unroll
  for (int nt = 0; nt < 4; ++nt) {
    float b = bv[nt * 16 + c15];
#pragma unroll
    for (int mt = 0; mt < 2; ++mt) V[mt][nt] += b;
  }

  // ---- attn = sum_k max(w - tau, 0) * V ; x_att = 2*feats + attn; LN ----
  float x4[4];
#pragma unroll
  for (int nt = 0; nt < 4; ++nt) {
    float t4 = __shfl(tau, nt * 16 + c15, 64);
    float ssum = 0.f;
#pragma unroll
    for (int mt = 0; mt < 2; ++mt) {
      floatx4 w4 = ldCread(Tw, c15, g, mt, nt);
#pragma unroll
      for (int r = 0; r < 4; ++r)
        ssum += fmaxf(w4[r] - t4, 0.f) * V[mt][nt][r];
    }
    ssum += __shfl_xor(ssum, 16, 64);
    ssum += __shfl_xor(ssum, 32, 64);
    x4[nt] = 2.f * feats[(size_t)n * 64 + nt * 16 + c15] + ssum;
  }

  float sum = x4[0] + x4[1] + x4[2] + x4[3];
  float sum2 = x4[0] * x4[0] + x4[1] * x4[1] + x4[2] * x4[2] + x4[3] * x4[3];
#pragma unroll
  for (int m = 1; m < 16; m <<= 1) {
    sum += __shfl_xor(sum, m, 64);
    sum2 += __shfl_xor(sum2, m, 64);
  }
  float mean = sum * (1.f / 64.f);
  float var = sum2 * (1.f / 64.f) - mean * mean;
  float inv = rsqrtf(var + EPSF);
  h_out[(size_t)n * 64 + lane] =
      (_Float16)(g_att[lane] * (x4[g] - mean) * inv + b_att[lane]);
}

// ---------------------------------------------------------------------------
// Kernel B v4: graph conv + FFN + LN. Block = 16 points.
// Phase 1: scalar-indexed coalesced gather; Phase 2 (wave 0): MFMA + LN.
// ---------------------------------------------------------------------------
__global__ __launch_bounds__(256) void gconv_kernel(
    const float* __restrict__ coords, const _Float16* __restrict__ h,
    const _Float16* __restrict__ wtg, const float* __restrict__ Wsg,
    const float* __restrict__ bsg, const float* __restrict__ bf,
    const float* __restrict__ g_ff, const float* __restrict__ b_ff,
    const int* __restrict__ knn, float* __restrict__ out)
{
  __shared__ float agg_s[16 * 68];
  __shared__ float cm_s[16 * 4];
  __shared__ float T2[2048];
  const int wv = __builtin_amdgcn_readfirstlane(threadIdx.x >> 6);
  const int lane = threadIdx.x & 63;
  const int c15 = lane & 15, g = lane >> 4;
  const int n0 = blockIdx.x * 16;
  const float inv33 = 1.0f / 33.0f;
  const _Float16* wt_sg = wtg + 5 * 4096;
  const _Float16* wt_f  = wtg + 6 * 4096;

#pragma unroll
  for (int i = 0; i < 4; ++i) {
    int pl = wv * 4 + i;
    int p = n0 + pl;
    const int* row = knn + (size_t)p * 33;
    float acc = (float)h[(size_t)p * 64 + lane];
#pragma unroll 8
    for (int k = 1; k <= 32; ++k) {
      int idx = __builtin_amdgcn_readfirstlane(row[k]);
      acc += (float)h[(size_t)idx * 64 + lane];
    }
    agg_s[pl * 68 + lane] = acc * inv33;

    float sx = 0.f, sy = 0.f, sz = 0.f;
    if (lane < 33) {
      int src = (lane == 0) ? p : row[lane];
      sx = coords[(size_t)src * 3];
      sy = coords[(size_t)src * 3 + 1];
      sz = coords[(size_t)src * 3 + 2];
    }
#pragma unroll
    for (int m = 1; m < 64; m <<= 1) {
      sx += __shfl_xor(sx, m, 64);
      sy += __shfl_xor(sy, m, 64);
      sz += __shfl_xor(sz, m, 64);
    }
    if (lane == 0) {
      cm_s[pl * 4 + 0] = sx * inv33;
      cm_s[pl * 4 + 1] = sy * inv33;
      cm_s[pl * 4 + 2] = sz * inv33;
    }
  }
  __syncthreads();
  if (wv != 0) return;

  half8 aA[2];
#pragma unroll
  for (int ks = 0; ks < 2; ++ks) {
    const float* pr = agg_s + c15 * 68 + ks * 32 + g * 8;
    float4 u0 = *(const float4*)pr, u1 = *(const float4*)(pr + 4);
    aA[ks][0] = (_Float16)u0.x; aA[ks][1] = (_Float16)u0.y;
    aA[ks][2] = (_Float16)u0.z; aA[ks][3] = (_Float16)u0.w;
    aA[ks][4] = (_Float16)u1.x; aA[ks][5] = (_Float16)u1.y;
    aA[ks][6] = (_Float16)u1.z; aA[ks][7] = (_Float16)u1.w;
  }

  float cmx[4], cmy[4], cmz[4];
#pragma unroll
  for (int r = 0; r < 4; ++r) {
    int pl = g * 4 + r;
    cmx[r] = cm_s[pl * 4 + 0];
    cmy[r] = cm_s[pl * 4 + 1];
    cmz[r] = cm_s[pl * 4 + 2];
  }

  {
    floatx4 C1[4] = {};
    domm1(wt_sg, aA, c15, g, C1);
#pragma unroll
    for (int nt = 0; nt < 4; ++nt) {
      int col = nt * 16 + c15;
      float b = bsg[col];
      float w64 = Wsg[4096 + col], w65 = Wsg[4160 + col], w66 = Wsg[4224 + col];
      floatx4 v;
#pragma unroll
      for (int r = 0; r < 4; ++r)
        v[r] = fmaxf(C1[nt][r] + b + cmx[r] * w64 + cmy[r] * w65 + cmz[r] * w66, 0.f);
      stC(T2, c15, g, 0, nt, v);
    }
  }
  __builtin_amdgcn_wave_barrier();
  half8 aT[2];
  aT[0] = ldA(T2, c15, g, 0, 0);
  aT[1] = ldA(T2, c15, g, 0, 1);

  floatx4 C2[4] = {};
  domm1(wt_f, aT, c15, g, C2);
#pragma unroll
  for (int nt = 0; nt < 4; ++nt) {
    int col = nt * 16 + c15;
    float b = bf[col];
#pragma unroll
    for (int r = 0; r < 4; ++r)
      C2[nt][r] += b + (float)h[(size_t)(n0 + g * 4 + r) * 64 + col];
  }
#pragma unroll
  for (int r = 0; r < 4; ++r) {
    float s = C2[0][r] + C2[1][r] + C2[2][r] + C2[3][r];
    float s2 = C2[0][r] * C2[0][r] + C2[1][r] * C2[1][r] +
               C2[2][r] * C2[2][r] + C2[3][r] * C2[3][r];
#pragma unroll
    for (int m = 1; m < 16; m <<= 1) {
      s += __shfl_xor(s, m, 64);
      s2 += __shfl_xor(s2, m, 64);
    }
    float mean = s * (1.f / 64.f);
    float var = s2 * (1.f / 64.f) - mean * mean;
    float inv = rsqrtf(var + EPSF);
    int prow = n0 + g * 4 + r;
#pragma unroll
    for (int nt = 0; nt < 4; ++nt) {
      int col = nt * 16 + c15;
      out[(size_t)prow * 64 + col] =
          g_ff[col] * (C2[nt][r] - mean) * inv + b_ff[col];
    }
  }
}

extern "C" void kernel_launch(void* const* d_in, const int* in_sizes, int n_in,
                              void* d_out, int out_size, void* d_ws, size_t ws_size,
                              hipStream_t stream) {
  (void)in_sizes; (void)n_in; (void)out_size; (void)ws_size;
  const float* coords = (const float*)d_in[0];
  const float* feats  = (const float*)d_in[1];
  const float* Wq  = (const float*)d_in[2];  const float* bq  = (const float*)d_in[3];
  const float* Wk  = (const float*)d_in[4];  const float* bk  = (const float*)d_in[5];
  const float* Wv  = (const float*)d_in[6];  const float* bv  = (const float*)d_in[7];
  const float* Wl1 = (const float*)d_in[8];  const float* bl1 = (const float*)d_in[9];
  const float* Wl2 = (const float*)d_in[10]; const float* bl2 = (const float*)d_in[11];
  const float* Ww1 = (const float*)d_in[12]; const float* bw1 = (const float*)d_in[13];
  const float* Ww2 = (const float*)d_in[14]; const float* bw2 = (const float*)d_in[15];
  const float* g_att = (const float*)d_in[16]; const float* b_att = (const float*)d_in[17];
  const float* Wsg = (const float*)d_in[18]; const float* bsg = (const float*)d_in[19];
  const float* Wf  = (const float*)d_in[20]; const float* bf  = (const float*)d_in[21];
  const float* g_ff = (const float*)d_in[22]; const float* b_ff = (const float*)d_in[23];
  const int* knn = (const int*)d_in[24];

  // ws: [0, 2.56MB) h fp16 | [2.56MB, +56KB) swizzled weights | Qh fp16
  _Float16* h   = (_Float16*)d_ws;
  _Float16* wtg = (_Float16*)((char*)d_ws + 2621440);
  _Float16* Qh  = (_Float16*)((char*)d_ws + 2621440 + 57344);
  float* out = (float*)d_out;

  prep_q_kernel<<<dim3(164), dim3(256), 0, stream>>>(
      Wl2, Wv, Wk, Ww1, Ww2, Wsg, Wf, Wq, feats, bq, wtg, Qh);
  attn_kernel<<<dim3(NPTS / 4), dim3(256), 0, stream>>>(
      coords, feats, bk, bv, Wl1, bl1, bl2, bw1, bw2,
      g_att, b_att, knn, wtg, Qh, h);
  gconv_kernel<<<dim3(NPTS / 16), dim3(256), 0, stream>>>(
      coords, h, wtg, Wsg, bsg, bf, g_ff, b_ff, knn, out);
}

// Round 13
// 212.122 us; speedup vs baseline: 1.2301x; 1.2301x over previous
//
#include <hip/hip_runtime.h>

#define NPTS 20000
#define EPSF 1e-5f

typedef _Float16 half8 __attribute__((ext_vector_type(8)));
typedef float floatx4 __attribute__((ext_vector_type(4)));

// ---------------------------------------------------------------------------
// B-fragment: frag[j] = W[32ks+8g+j][16nt+c15], from swizzled fp16 weights:
//   [k][d] -> d*64 + (((k>>3)^(d&7))<<3) + (k&7)
// ---------------------------------------------------------------------------
__device__ __forceinline__ half8 ldWt(const _Float16* __restrict__ w,
                                      int c15, int g, int nt, int ks) {
  int c = nt * 16 + c15;
  int kg = ks * 4 + g;
  return *(const half8*)(w + c * 64 + ((kg ^ (c & 7)) << 3));
}

// B-fragment directly from fp32 row-major W (one-shot use, L2-hot)
__device__ __forceinline__ half8 ldWtF32(const float* __restrict__ W,
                                         int c15, int g, int nt, int ks) {
  int c = nt * 16 + c15;
  half8 r;
#pragma unroll
  for (int j = 0; j < 8; ++j) r[j] = (_Float16)W[(ks * 32 + g * 8 + j) * 64 + c];
  return r;
}

// Per-wave transpose buffer T: 64 cols x 32 rows fp32, XOR-swizzled chunks:
// [col][row] -> col*32 + (((row>>2)^(col&7))<<2) + (row&3)
__device__ __forceinline__ void stC(float* __restrict__ Tw, int c15, int g,
                                    int mt, int nt, floatx4 v) {
  int col = nt * 16 + c15;
  int chunk = mt * 4 + g;
  *(floatx4*)(Tw + col * 32 + ((chunk ^ (col & 7)) << 2)) = v;
}

__device__ __forceinline__ floatx4 ldCread(const float* __restrict__ Tw,
                                           int c15, int g, int mt, int nt) {
  int col = nt * 16 + c15;
  int chunk = mt * 4 + g;
  return *(const floatx4*)(Tw + col * 32 + ((chunk ^ (col & 7)) << 2));
}

// A-fragment from T: frag[j] = X[16mt+c15][32ks+8g+j] (fp32 -> fp16)
__device__ __forceinline__ half8 ldA(const float* __restrict__ Tw,
                                     int c15, int g, int mt, int ks) {
  int m = mt * 16 + c15;
  half8 r;
#pragma unroll
  for (int j = 0; j < 8; ++j) {
    int c = ks * 32 + g * 8 + j;                // c&7 == j
    r[j] = (_Float16)Tw[c * 32 + (((m >> 2) ^ j) << 2) + (m & 3)];
  }
  return r;
}

__device__ __forceinline__ void ldAfrags(const float* __restrict__ Tw,
                                         int c15, int g, half8 a[2][2]) {
#pragma unroll
  for (int mt = 0; mt < 2; ++mt)
#pragma unroll
    for (int ks = 0; ks < 2; ++ks) a[mt][ks] = ldA(Tw, c15, g, mt, ks);
}

__device__ __forceinline__ void domm(const _Float16* __restrict__ w,
                                     const half8 a[2][2], int c15, int g,
                                     floatx4 acc[2][4]) {
#pragma unroll
  for (int ks = 0; ks < 2; ++ks)
#pragma unroll
    for (int nt = 0; nt < 4; ++nt) {
      half8 b = ldWt(w, c15, g, nt, ks);
#pragma unroll
      for (int mt = 0; mt < 2; ++mt)
        acc[mt][nt] = __builtin_amdgcn_mfma_f32_16x16x32_f16(a[mt][ks], b, acc[mt][nt], 0, 0, 0);
    }
}

// single-mt (16-row) variant for gconv
__device__ __forceinline__ void domm1(const _Float16* __restrict__ w,
                                      const half8 a[2], int c15, int g,
                                      floatx4 acc[4]) {
#pragma unroll
  for (int ks = 0; ks < 2; ++ks)
#pragma unroll
    for (int nt = 0; nt < 4; ++nt) {
      half8 b = ldWt(w, c15, g, nt, ks);
      acc[nt] = __builtin_amdgcn_mfma_f32_16x16x32_f16(a[ks], b, acc[nt], 0, 0, 0);
    }
}

// ---------------------------------------------------------------------------
// Fused weight-prep (blocks 0..6) + Q precompute (blocks 7..163).
// prep order: Wl2, Wv, Wk, Ww1, Ww2, Wsg[0:64], Wf
// ---------------------------------------------------------------------------
__global__ __launch_bounds__(256) void prep_q_kernel(
    const float* __restrict__ Wl2, const float* __restrict__ Wv,
    const float* __restrict__ Wk, const float* __restrict__ Ww1,
    const float* __restrict__ Ww2, const float* __restrict__ Wsg,
    const float* __restrict__ Wf, const float* __restrict__ Wq,
    const float* __restrict__ feats, const float* __restrict__ bq,
    _Float16* __restrict__ wtg, _Float16* __restrict__ Qh)
{
  if (blockIdx.x < 7) {
    const float* srcs[7] = {Wl2, Wv, Wk, Ww1, Ww2, Wsg, Wf};
    const float* src = srcs[blockIdx.x];
    _Float16* dst = wtg + blockIdx.x * 4096;
    int t = threadIdx.x;
#pragma unroll
    for (int i = 0; i < 16; ++i) {
      int lin = i * 256 + t;            // = k*64 + d
      int k = lin >> 6, d = lin & 63;
      dst[d * 64 + (((k >> 3) ^ (d & 7)) << 3) + (k & 7)] = (_Float16)src[lin];
    }
    return;
  }
  // ---- Q = relu(feats @ Wq + bq), 32 points/wave ----
  const int wv = threadIdx.x >> 6, lane = threadIdx.x & 63;
  const int c15 = lane & 15, g = lane >> 4;
  const int n0 = ((blockIdx.x - 7) * 4 + wv) * 32;

  half8 a[2][2];
#pragma unroll
  for (int mt = 0; mt < 2; ++mt) {
    int r = n0 + mt * 16 + c15;
    if (r > NPTS - 1) r = NPTS - 1;
#pragma unroll
    for (int ks = 0; ks < 2; ++ks) {
      const float* p = feats + (size_t)r * 64 + ks * 32 + g * 8;
      float4 u0 = *(const float4*)p, u1 = *(const float4*)(p + 4);
      a[mt][ks][0] = (_Float16)u0.x; a[mt][ks][1] = (_Float16)u0.y;
      a[mt][ks][2] = (_Float16)u0.z; a[mt][ks][3] = (_Float16)u0.w;
      a[mt][ks][4] = (_Float16)u1.x; a[mt][ks][5] = (_Float16)u1.y;
      a[mt][ks][6] = (_Float16)u1.z; a[mt][ks][7] = (_Float16)u1.w;
    }
  }
  floatx4 acc[2][4] = {};
#pragma unroll
  for (int ks = 0; ks < 2; ++ks)
#pragma unroll
    for (int nt = 0; nt < 4; ++nt) {
      half8 b = ldWtF32(Wq, c15, g, nt, ks);
#pragma unroll
      for (int mt = 0; mt < 2; ++mt)
        acc[mt][nt] = __builtin_amdgcn_mfma_f32_16x16x32_f16(a[mt][ks], b, acc[mt][nt], 0, 0, 0);
    }
#pragma unroll
  for (int nt = 0; nt < 4; ++nt) {
    float bqv = bq[nt * 16 + c15];
#pragma unroll
    for (int mt = 0; mt < 2; ++mt)
#pragma unroll
      for (int r = 0; r < 4; ++r) {
        int n = n0 + mt * 16 + g * 4 + r;
        if (n < NPTS)
          Qh[(size_t)n * 64 + nt * 16 + c15] = (_Float16)fmaxf(acc[mt][nt][r] + bqv, 0.f);
      }
  }
}

// ---------------------------------------------------------------------------
// Kernel A: fused per-point attention; one wave per point, MFMA matmuls.
// FINAL CONFIG (occupancy bracketed: (256,3) R5 -8µs occupancy-loss;
// (256,4) optimum; (256,5) R12 -49µs spill-storm. Register budget: exactly
// one live 32-acc fp32 structure + aP fits the 128-unified cap — R9/R10
// additions spilled.)
// ---------------------------------------------------------------------------
__global__ __launch_bounds__(256, 4) void attn_kernel(
    const float* __restrict__ coords, const float* __restrict__ feats,
    const float* __restrict__ bk, const float* __restrict__ bv,
    const float* __restrict__ Wl1, const float* __restrict__ bl1,
    const float* __restrict__ bl2, const float* __restrict__ bw1,
    const float* __restrict__ bw2, const float* __restrict__ g_att,
    const float* __restrict__ b_att, const int* __restrict__ knn,
    const _Float16* __restrict__ wtg, const _Float16* __restrict__ Qh,
    _Float16* __restrict__ h_out)
{
  __shared__ float Tsh[4][2048];
  const int wv = threadIdx.x >> 6, lane = threadIdx.x & 63;
  const int c15 = lane & 15, g = lane >> 4;
  const int n = blockIdx.x * 4 + wv;
  float* Tw = Tsh[wv];
  const int* row = knn + (size_t)n * 33;

  const _Float16* wt_l2 = wtg;
  const _Float16* wt_v  = wtg + 4096;
  const _Float16* wt_k  = wtg + 8192;
  const _Float16* wt_w1 = wtg + 12288;
  const _Float16* wt_w2 = wtg + 16384;

  // ---- h1 = relu(diff @ Wl1 + bl1), built directly in A-layout ----
  half8 aH[2][2];
  {
    float cnx = coords[(size_t)n * 3], cny = coords[(size_t)n * 3 + 1],
          cnz = coords[(size_t)n * 3 + 2];
#pragma unroll
    for (int ks = 0; ks < 2; ++ks) {
      int c0 = ks * 32 + g * 8;
      float4 wx0 = *(const float4*)(Wl1 + c0),       wx1 = *(const float4*)(Wl1 + c0 + 4);
      float4 wy0 = *(const float4*)(Wl1 + 64 + c0),  wy1 = *(const float4*)(Wl1 + 64 + c0 + 4);
      float4 wz0 = *(const float4*)(Wl1 + 128 + c0), wz1 = *(const float4*)(Wl1 + 128 + c0 + 4);
      float4 bb0 = *(const float4*)(bl1 + c0),       bb1 = *(const float4*)(bl1 + c0 + 4);
      float wx[8] = {wx0.x,wx0.y,wx0.z,wx0.w,wx1.x,wx1.y,wx1.z,wx1.w};
      float wy[8] = {wy0.x,wy0.y,wy0.z,wy0.w,wy1.x,wy1.y,wy1.z,wy1.w};
      float wz[8] = {wz0.x,wz0.y,wz0.z,wz0.w,wz1.x,wz1.y,wz1.z,wz1.w};
      float bb[8] = {bb0.x,bb0.y,bb0.z,bb0.w,bb1.x,bb1.y,bb1.z,bb1.w};
#pragma unroll
      for (int mt = 0; mt < 2; ++mt) {
        int id = row[mt * 16 + c15];
        float dx = coords[(size_t)id * 3] - cnx;
        float dy = coords[(size_t)id * 3 + 1] - cny;
        float dz = coords[(size_t)id * 3 + 2] - cnz;
#pragma unroll
        for (int j = 0; j < 8; ++j)
          aH[mt][ks][j] = (_Float16)fmaxf(dx * wx[j] + dy * wy[j] + dz * wz[j] + bb[j], 0.f);
      }
    }
  }

  // ---- fc = h1 @ Wl2 + bl2 -> straight to T (accs die here) ----
  {
    floatx4 fcacc[2][4] = {};
    domm(wt_l2, aH, c15, g, fcacc);
#pragma unroll
    for (int nt = 0; nt < 4; ++nt) {
      float b = bl2[nt * 16 + c15];
#pragma unroll
      for (int mt = 0; mt < 2; ++mt) stC(Tw, c15, g, mt, nt, fcacc[mt][nt] + b);
    }
  }
  __builtin_amdgcn_wave_barrier();

  // ---- aP = fp16(fc + feats[idx]) built directly in A-layout ----
  half8 aP[2][2];
#pragma unroll
  for (int mt = 0; mt < 2; ++mt) {
    int m = mt * 16 + c15;
    int rn = row[m];
#pragma unroll
    for (int ks = 0; ks < 2; ++ks) {
      const float* fp = feats + (size_t)rn * 64 + ks * 32 + g * 8;
      float4 u0 = *(const float4*)fp, u1 = *(const float4*)(fp + 4);
      float fv[8] = {u0.x,u0.y,u0.z,u0.w,u1.x,u1.y,u1.z,u1.w};
#pragma unroll
      for (int j = 0; j < 8; ++j) {
        int c = ks * 32 + g * 8 + j;              // c&7 == j
        float fcv = Tw[c * 32 + (((m >> 2) ^ j) << 2) + (m & 3)];
        aP[mt][ks][j] = (_Float16)(fcv + fv[j]);
      }
    }
  }
  __builtin_amdgcn_wave_barrier();

  // ---- KR = pe @ Wk ; rel = (relu(KR+bk) - Q) * fc, in place over fc ----
  {
    floatx4 KR[2][4] = {};
    domm(wt_k, aP, c15, g, KR);
    __builtin_amdgcn_wave_barrier();
#pragma unroll
    for (int nt = 0; nt < 4; ++nt) {
      float bkv = bk[nt * 16 + c15];
      float q4 = (float)Qh[(size_t)n * 64 + nt * 16 + c15];
#pragma unroll
      for (int mt = 0; mt < 2; ++mt) {
        floatx4 fcq = ldCread(Tw, c15, g, mt, nt);
        floatx4 v;
#pragma unroll
        for (int r = 0; r < 4; ++r)
          v[r] = (fmaxf(KR[mt][nt][r] + bkv, 0.f) - q4) * fcq[r];
        stC(Tw, c15, g, mt, nt, v);
      }
    }
  }
  __builtin_amdgcn_wave_barrier();
  half8 aR[2][2];
  ldAfrags(Tw, c15, g, aR);

  // ---- w1 = relu(rel @ Ww1 + bw1) -> T ----
  {
    floatx4 W1[2][4] = {};
    domm(wt_w1, aR, c15, g, W1);
    __builtin_amdgcn_wave_barrier();
#pragma unroll
    for (int nt = 0; nt < 4; ++nt) {
      float b = bw1[nt * 16 + c15];
#pragma unroll
      for (int mt = 0; mt < 2; ++mt) {
        floatx4 v;
#pragma unroll
        for (int r = 0; r < 4; ++r) v[r] = fmaxf(W1[mt][nt][r] + b, 0.f);
        stC(Tw, c15, g, mt, nt, v);
      }
    }
  }
  __builtin_amdgcn_wave_barrier();
  half8 aW[2][2];
  ldAfrags(Tw, c15, g, aW);

  // ---- w = w1 @ Ww2 + bw2 -> T ----
  {
    floatx4 WW[2][4] = {};
    domm(wt_w2, aW, c15, g, WW);
    __builtin_amdgcn_wave_barrier();
#pragma unroll
    for (int nt = 0; nt < 4; ++nt) {
      float b = bw2[nt * 16 + c15];
#pragma unroll
      for (int mt = 0; mt < 2; ++mt) stC(Tw, c15, g, mt, nt, WW[mt][nt] + b);
    }
  }
  __builtin_amdgcn_wave_barrier();

  // ---- sparsemax: lane d = lane sorts column d (from T) ----
  float tau;
  {
    float a[32];
#pragma unroll
    for (int i = 0; i < 8; ++i) {
      floatx4 ch = *(const floatx4*)(Tw + lane * 32 + ((i ^ (lane & 7)) << 2));
#pragma unroll
      for (int r = 0; r < 4; ++r) a[i * 4 + r] = ch[r];
    }
#pragma unroll
    for (int size = 2; size <= 32; size <<= 1) {
#pragma unroll
      for (int stride = size >> 1; stride > 0; stride >>= 1) {
#pragma unroll
        for (int i = 0; i < 32; ++i) {
          int j = i ^ stride;
          if (j > i) {
            float x = a[i], y = a[j];
            float lo = fminf(x, y), hi = fmaxf(x, y);
            bool up = ((i & size) == 0);
            a[i] = up ? hi : lo;
            a[j] = up ? lo : hi;
          }
        }
      }
    }
    float csum = 0.f, csel = 0.f;
    int ksup = 1;
#pragma unroll
    for (int i = 0; i < 32; ++i) {
      csum += a[i];
      if (1.0f + (float)(i + 1) * a[i] > csum) { ksup = i + 1; csel = csum; }
    }
    tau = (csel - 1.0f) / (float)ksup;
  }

  // ---- V = pe @ Wv + bv (aP still live; sort regs dead) ----
  floatx4 V[2][4] = {};
  domm(wt_v, aP, c15, g, V);
#pragma unroll
  for (int nt = 0; nt < 4; ++nt) {
    float b = bv[nt * 16 + c15];
#pragma unroll
    for (int mt = 0; mt < 2; ++mt) V[mt][nt] += b;
  }

  // ---- attn = sum_k max(w - tau, 0) * V ; x_att = 2*feats + attn; LN ----
  float x4[4];
#pragma unroll
  for (int nt = 0; nt < 4; ++nt) {
    float t4 = __shfl(tau, nt * 16 + c15, 64);
    float ssum = 0.f;
#pragma unroll
    for (int mt = 0; mt < 2; ++mt) {
      floatx4 w4 = ldCread(Tw, c15, g, mt, nt);
#pragma unroll
      for (int r = 0; r < 4; ++r)
        ssum += fmaxf(w4[r] - t4, 0.f) * V[mt][nt][r];
    }
    ssum += __shfl_xor(ssum, 16, 64);
    ssum += __shfl_xor(ssum, 32, 64);
    x4[nt] = 2.f * feats[(size_t)n * 64 + nt * 16 + c15] + ssum;
  }

  float sum = x4[0] + x4[1] + x4[2] + x4[3];
  float sum2 = x4[0] * x4[0] + x4[1] * x4[1] + x4[2] * x4[2] + x4[3] * x4[3];
#pragma unroll
  for (int m = 1; m < 16; m <<= 1) {
    sum += __shfl_xor(sum, m, 64);
    sum2 += __shfl_xor(sum2, m, 64);
  }
  float mean = sum * (1.f / 64.f);
  float var = sum2 * (1.f / 64.f) - mean * mean;
  float inv = rsqrtf(var + EPSF);
  h_out[(size_t)n * 64 + lane] =
      (_Float16)(g_att[lane] * (x4[g] - mean) * inv + b_att[lane]);
}

// ---------------------------------------------------------------------------
// Kernel B v4: graph conv + FFN + LN. Block = 16 points.
// Phase 1: scalar-indexed coalesced gather; Phase 2 (wave 0): MFMA + LN.
// ---------------------------------------------------------------------------
__global__ __launch_bounds__(256) void gconv_kernel(
    const float* __restrict__ coords, const _Float16* __restrict__ h,
    const _Float16* __restrict__ wtg, const float* __restrict__ Wsg,
    const float* __restrict__ bsg, const float* __restrict__ bf,
    const float* __restrict__ g_ff, const float* __restrict__ b_ff,
    const int* __restrict__ knn, float* __restrict__ out)
{
  __shared__ float agg_s[16 * 68];
  __shared__ float cm_s[16 * 4];
  __shared__ float T2[2048];
  const int wv = __builtin_amdgcn_readfirstlane(threadIdx.x >> 6);
  const int lane = threadIdx.x & 63;
  const int c15 = lane & 15, g = lane >> 4;
  const int n0 = blockIdx.x * 16;
  const float inv33 = 1.0f / 33.0f;
  const _Float16* wt_sg = wtg + 5 * 4096;
  const _Float16* wt_f  = wtg + 6 * 4096;

#pragma unroll
  for (int i = 0; i < 4; ++i) {
    int pl = wv * 4 + i;
    int p = n0 + pl;
    const int* row = knn + (size_t)p * 33;
    float acc = (float)h[(size_t)p * 64 + lane];
#pragma unroll 8
    for (int k = 1; k <= 32; ++k) {
      int idx = __builtin_amdgcn_readfirstlane(row[k]);
      acc += (float)h[(size_t)idx * 64 + lane];
    }
    agg_s[pl * 68 + lane] = acc * inv33;

    float sx = 0.f, sy = 0.f, sz = 0.f;
    if (lane < 33) {
      int src = (lane == 0) ? p : row[lane];
      sx = coords[(size_t)src * 3];
      sy = coords[(size_t)src * 3 + 1];
      sz = coords[(size_t)src * 3 + 2];
    }
#pragma unroll
    for (int m = 1; m < 64; m <<= 1) {
      sx += __shfl_xor(sx, m, 64);
      sy += __shfl_xor(sy, m, 64);
      sz += __shfl_xor(sz, m, 64);
    }
    if (lane == 0) {
      cm_s[pl * 4 + 0] = sx * inv33;
      cm_s[pl * 4 + 1] = sy * inv33;
      cm_s[pl * 4 + 2] = sz * inv33;
    }
  }
  __syncthreads();
  if (wv != 0) return;

  half8 aA[2];
#pragma unroll
  for (int ks = 0; ks < 2; ++ks) {
    const float* pr = agg_s + c15 * 68 + ks * 32 + g * 8;
    float4 u0 = *(const float4*)pr, u1 = *(const float4*)(pr + 4);
    aA[ks][0] = (_Float16)u0.x; aA[ks][1] = (_Float16)u0.y;
    aA[ks][2] = (_Float16)u0.z; aA[ks][3] = (_Float16)u0.w;
    aA[ks][4] = (_Float16)u1.x; aA[ks][5] = (_Float16)u1.y;
    aA[ks][6] = (_Float16)u1.z; aA[ks][7] = (_Float16)u1.w;
  }

  float cmx[4], cmy[4], cmz[4];
#pragma unroll
  for (int r = 0; r < 4; ++r) {
    int pl = g * 4 + r;
    cmx[r] = cm_s[pl * 4 + 0];
    cmy[r] = cm_s[pl * 4 + 1];
    cmz[r] = cm_s[pl * 4 + 2];
  }

  {
    floatx4 C1[4] = {};
    domm1(wt_sg, aA, c15, g, C1);
#pragma unroll
    for (int nt = 0; nt < 4; ++nt) {
      int col = nt * 16 + c15;
      float b = bsg[col];
      float w64 = Wsg[4096 + col], w65 = Wsg[4160 + col], w66 = Wsg[4224 + col];
      floatx4 v;
#pragma unroll
      for (int r = 0; r < 4; ++r)
        v[r] = fmaxf(C1[nt][r] + b + cmx[r] * w64 + cmy[r] * w65 + cmz[r] * w66, 0.f);
      stC(T2, c15, g, 0, nt, v);
    }
  }
  __builtin_amdgcn_wave_barrier();
  half8 aT[2];
  aT[0] = ldA(T2, c15, g, 0, 0);
  aT[1] = ldA(T2, c15, g, 0, 1);

  floatx4 C2[4] = {};
  domm1(wt_f, aT, c15, g, C2);
#pragma unroll
  for (int nt = 0; nt < 4; ++nt) {
    int col = nt * 16 + c15;
    float b = bf[col];
#pragma unroll
    for (int r = 0; r < 4; ++r)
      C2[nt][r] += b + (float)h[(size_t)(n0 + g * 4 + r) * 64 + col];
  }
#pragma unroll
  for (int r = 0; r < 4; ++r) {
    float s = C2[0][r] + C2[1][r] + C2[2][r] + C2[3][r];
    float s2 = C2[0][r] * C2[0][r] + C2[1][r] * C2[1][r] +
               C2[2][r] * C2[2][r] + C2[3][r] * C2[3][r];
#pragma unroll
    for (int m = 1; m < 16; m <<= 1) {
      s += __shfl_xor(s, m, 64);
      s2 += __shfl_xor(s2, m, 64);
    }
    float mean = s * (1.f / 64.f);
    float var = s2 * (1.f / 64.f) - mean * mean;
    float inv = rsqrtf(var + EPSF);
    int prow = n0 + g * 4 + r;
#pragma unroll
    for (int nt = 0; nt < 4; ++nt) {
      int col = nt * 16 + c15;
      out[(size_t)prow * 64 + col] =
          g_ff[col] * (C2[nt][r] - mean) * inv + b_ff[col];
    }
  }
}

extern "C" void kernel_launch(void* const* d_in, const int* in_sizes, int n_in,
                              void* d_out, int out_size, void* d_ws, size_t ws_size,
                              hipStream_t stream) {
  (void)in_sizes; (void)n_in; (void)out_size; (void)ws_size;
  const float* coords = (const float*)d_in[0];
  const float* feats  = (const float*)d_in[1];
  const float* Wq  = (const float*)d_in[2];  const float* bq  = (const float*)d_in[3];
  const float* Wk  = (const float*)d_in[4];  const float* bk  = (const float*)d_in[5];
  const float* Wv  = (const float*)d_in[6];  const float* bv  = (const float*)d_in[7];
  const float* Wl1 = (const float*)d_in[8];  const float* bl1 = (const float*)d_in[9];
  const float* Wl2 = (const float*)d_in[10]; const float* bl2 = (const float*)d_in[11];
  const float* Ww1 = (const float*)d_in[12]; const float* bw1 = (const float*)d_in[13];
  const float* Ww2 = (const float*)d_in[14]; const float* bw2 = (const float*)d_in[15];
  const float* g_att = (const float*)d_in[16]; const float* b_att = (const float*)d_in[17];
  const float* Wsg = (const float*)d_in[18]; const float* bsg = (const float*)d_in[19];
  const float* Wf  = (const float*)d_in[20]; const float* bf  = (const float*)d_in[21];
  const float* g_ff = (const float*)d_in[22]; const float* b_ff = (const float*)d_in[23];
  const int* knn = (const int*)d_in[24];

  // ws: [0, 2.56MB) h fp16 | [2.56MB, +56KB) swizzled weights | Qh fp16
  _Float16* h   = (_Float16*)d_ws;
  _Float16* wtg = (_Float16*)((char*)d_ws + 2621440);
  _Float16* Qh  = (_Float16*)((char*)d_ws + 2621440 + 57344);
  float* out = (float*)d_out;

  prep_q_kernel<<<dim3(164), dim3(256), 0, stream>>>(
      Wl2, Wv, Wk, Ww1, Ww2, Wsg, Wf, Wq, feats, bq, wtg, Qh);
  attn_kernel<<<dim3(NPTS / 4), dim3(256), 0, stream>>>(
      coords, feats, bk, bv, Wl1, bl1, bl2, bw1, bw2,
      g_att, b_att, knn, wtg, Qh, h);
  gconv_kernel<<<dim3(NPTS / 16), dim3(256), 0, stream>>>(
      coords, h, wtg, Wsg, bsg, bf, g_ff, b_ff, knn, out);
}